// Round 8
// baseline (381.995 us; speedup 1.0000x reference)
//
#include <hip/hip_runtime.h>
#include <hip/hip_bf16.h>

// Problem constants
static constexpr int Bc   = 2;
static constexpr int Nc   = 512;
static constexpr int Mc   = 512;
static constexpr int D0c  = 1024;
static constexpr int Dc   = 100;   // embed dim
static constexpr int Hc   = 50;    // hidden channels
static constexpr long long NMc = (long long)Nc * Mc; // 262144

typedef __attribute__((ext_vector_type(8))) short short8v;
typedef __attribute__((ext_vector_type(4))) float f32x4;

// trunc-bf16 pack: low16 = a[31:16], high16 = b[31:16]  (1 v_perm_b32)
__device__ __forceinline__ unsigned pk_hi(float a, float b) {
  return __builtin_amdgcn_perm(__float_as_uint(b), __float_as_uint(a), 0x07060302u);
}
__device__ __forceinline__ float trunc16(float x) {
  return __uint_as_float(__float_as_uint(x) & 0xffff0000u);
}
// f32 -> bf16 bits, round-to-nearest-even (x >= 0 finite here)
__device__ __forceinline__ unsigned short f2bf_rne(float x) {
  const unsigned b = __float_as_uint(x);
  const unsigned r = b + 0x7fffu + ((b >> 16) & 1u);
  return (unsigned short)(r >> 16);
}

// ---------------------------------------------------------------------------
// k_prep: blocks 0..255 = embed (e = relu(x @ W_proj + b_proj), fp32 acc);
// block 256 = wsplit fragments + gacc zeroing.  (merged to cut launch gaps)
// ---------------------------------------------------------------------------
__global__ __launch_bounds__(512) void k_prep(
    const float* __restrict__ x0, const float* __restrict__ x1,
    const float* __restrict__ Wp, const float* __restrict__ bp,
    const float* __restrict__ Whid,
    float* __restrict__ e0, float* __restrict__ e1,
    uint4* __restrict__ wsplit, double* __restrict__ gacc)
{
  const int t = threadIdx.x;
  if (blockIdx.x == 256) {
    // zero gacc (8 doubles) + ticket counter (int at dword 16)
    if (t < 18) ((int*)gacc)[t] = 0;
    // wsplit: 56 fragment sets, 8 lane-groups of 64
    const int grp = t >> 6, lane = t & 63;
    const int h_loc = lane & 15, g = lane >> 4;
    for (int fi = grp; fi < 56; fi += 8) {
      const int s  = fi >> 3;
      const int ht = (fi >> 1) & 3;
      const int hl = fi & 1;
      const int h = ht*16 + h_loc;
      uint dw[4] = {0u,0u,0u,0u};
      #pragma unroll
      for (int j = 0; j < 8; ++j) {
        const int p = j >> 2, q = j & 3;
        const int d = s*16 + g*4 + q;
        float wv = (h < Hc && d < Dc) ? Whid[(size_t)(p*Dc + d)*Hc + h] : 0.f;
        const uint bits = __float_as_uint(wv);
        const uint hi_bits = bits & 0xffff0000u;
        uint e16;
        if (hl == 0) e16 = hi_bits >> 16;
        else {
          const float lo = wv - __uint_as_float(hi_bits);
          e16 = __float_as_uint(lo) >> 16;
        }
        dw[j >> 1] |= e16 << (16 * (j & 1));
      }
      uint4 v; v.x = dw[0]; v.y = dw[1]; v.z = dw[2]; v.w = dw[3];
      wsplit[fi*64 + lane] = v;
    }
    return;
  }

  __shared__ float xs[8][1024];   // 32 KB
  const int rg0 = blockIdx.x * 8;

  #pragma unroll
  for (int i = 0; i < 4; ++i) {
    const int idx = i*512 + t;       // 0..2047
    const int r   = idx >> 8;        // 256 float4 per row
    const int c4  = idx & 255;
    const int rgs = rg0 + r;
    const float* src = (rgs < Bc*Nc) ? (x0 + (size_t)rgs * D0c)
                                     : (x1 + (size_t)(rgs - Bc*Nc) * D0c);
    *(float4*)&xs[r][c4*4] = *(const float4*)&src[c4*4];
  }
  __syncthreads();

  const int c = t & 127;
  const int q = t >> 7;         // 0..3
  if (c < Dc) {
    const int row0 = q*2, row1 = q*2 + 1;
    float acc0 = 0.f, acc1 = 0.f;
    for (int k = 0; k < D0c; k += 8) {
      float w[8];
      #pragma unroll
      for (int u = 0; u < 8; ++u) w[u] = Wp[(k+u)*Dc + c];
      const float4 xa0 = *(const float4*)&xs[row0][k];
      const float4 xb0 = *(const float4*)&xs[row0][k+4];
      const float4 xa1 = *(const float4*)&xs[row1][k];
      const float4 xb1 = *(const float4*)&xs[row1][k+4];
      acc0 = fmaf(xa0.x, w[0], acc0); acc1 = fmaf(xa1.x, w[0], acc1);
      acc0 = fmaf(xa0.y, w[1], acc0); acc1 = fmaf(xa1.y, w[1], acc1);
      acc0 = fmaf(xa0.z, w[2], acc0); acc1 = fmaf(xa1.z, w[2], acc1);
      acc0 = fmaf(xa0.w, w[3], acc0); acc1 = fmaf(xa1.w, w[3], acc1);
      acc0 = fmaf(xb0.x, w[4], acc0); acc1 = fmaf(xb1.x, w[4], acc1);
      acc0 = fmaf(xb0.y, w[5], acc0); acc1 = fmaf(xb1.y, w[5], acc1);
      acc0 = fmaf(xb0.z, w[6], acc0); acc1 = fmaf(xb1.z, w[6], acc1);
      acc0 = fmaf(xb0.w, w[7], acc0); acc1 = fmaf(xb1.w, w[7], acc1);
    }
    const float bias = bp[c];
    {
      const int rg = rg0 + row0;
      const float v = fmaxf(acc0 + bias, 0.f);
      if (rg < Bc*Nc) e0[(size_t)rg*Dc + c] = v;
      else            e1[(size_t)(rg - Bc*Nc)*Dc + c] = v;
    }
    {
      const int rg = rg0 + row1;
      const float v = fmaxf(acc1 + bias, 0.f);
      if (rg < Bc*Nc) e0[(size_t)rg*Dc + c] = v;
      else            e1[(size_t)(rg - Bc*Nc)*Dc + c] = v;
    }
  }
}

// ---------------------------------------------------------------------------
// k_hh (MFMA, split-bf16): block = 2 n-rows x 32 m; 4 waves, each a distinct
// (n,16m) pair and all 4 h-tiles. Output now stored as bf16 (RNE) -> half
// the write traffic and half the conv fetch.
// ---------------------------------------------------------------------------
__global__ __launch_bounds__(256, 4) void k_hh(
    const float* __restrict__ e0, const float* __restrict__ e1,
    const uint4* __restrict__ wsplit, const float* __restrict__ bhid,
    unsigned short* __restrict__ hh, int slab_n0, int slabh)
{
  const int b   = blockIdx.z;
  const int lr0 = blockIdx.y * 2;
  const int n0base = slab_n0 + lr0;
  if (n0base + 1 < 0 || n0base >= Nc) return;   // both rows out of range

  __shared__ float e1T[32][116];    // 14848 B (stride 116: 2-way only)
  __shared__ float e0s[2][112];     // 896 B
  __shared__ float biasl[64];       // 256 B
  __shared__ float ldsT[4][16][17]; // 4352 B

  const int t   = threadIdx.x;
  const int m0b = blockIdx.x * 32;

  { // stage e1T rows m0b..m0b+31, cols 0..111 (division-free)
    const int row = t >> 3;          // 0..31
    const int cb  = (t & 7) * 4;     // 0..28
    const float* src = e1 + (size_t)(b*Mc + m0b + row) * Dc;
    #pragma unroll
    for (int pass = 0; pass < 4; ++pass) {
      const int col = cb + pass*32;
      if (col < 112) {
        float4 v = {0.f,0.f,0.f,0.f};
        if (col < Dc) v = *(const float4*)&src[col];
        *(float4*)&e1T[row][col] = v;
      }
    }
  }
  { // stage e0s (2 rows, zero-padded / zero if n invalid)
    const int nl2 = t >> 7, col = t & 127;
    if (col < 112) {
      const int n = n0base + nl2;
      float v = 0.f;
      if ((unsigned)n < (unsigned)Nc && col < Dc)
        v = e0[(size_t)(b*Nc + n)*Dc + col];
      e0s[nl2][col] = v;
    }
  }
  if (t < 64) biasl[t] = (t < Hc) ? bhid[t] : 0.f;
  __syncthreads();

  const int w = t >> 6, lane = t & 63;
  const int cl = lane & 15, g = lane >> 4;
  const int nl   = w >> 1;             // n-local
  const int mrow = (w & 1) * 16 + cl;  // e1T row = m-local

  f32x4 acc0 = {0.f,0.f,0.f,0.f}, acc1 = {0.f,0.f,0.f,0.f};
  f32x4 acc2 = {0.f,0.f,0.f,0.f}, acc3 = {0.f,0.f,0.f,0.f};

  union U { uint4 u; short8v v; };
  const uint4* __restrict__ wq = wsplit + lane;

  #pragma unroll
  for (int s = 0; s < 7; ++s) {
    const int d0 = s*16 + g*4;
    const float4 E1 = *(const float4*)&e1T[mrow][d0];
    const float4 E0 = *(const float4*)&e0s[nl][d0];

    const float df0 = fabsf(E0.x - E1.x), df1 = fabsf(E0.y - E1.y),
                df2 = fabsf(E0.z - E1.z), df3 = fabsf(E0.w - E1.w);
    const float pm0 = E0.x*E1.x, pm1 = E0.y*E1.y,
                pm2 = E0.z*E1.z, pm3 = E0.w*E1.w;

    U ahi, alo;
    ahi.u.x = pk_hi(df0, df1); ahi.u.y = pk_hi(df2, df3);
    ahi.u.z = pk_hi(pm0, pm1); ahi.u.w = pk_hi(pm2, pm3);
    alo.u.x = pk_hi(df0 - trunc16(df0), df1 - trunc16(df1));
    alo.u.y = pk_hi(df2 - trunc16(df2), df3 - trunc16(df3));
    alo.u.z = pk_hi(pm0 - trunc16(pm0), pm1 - trunc16(pm1));
    alo.u.w = pk_hi(pm2 - trunc16(pm2), pm3 - trunc16(pm3));

    #pragma unroll
    for (int ht = 0; ht < 4; ++ht) {
      U whi, wlo;
      whi.u = wq[((s*4 + ht)*2 + 0)*64];
      wlo.u = wq[((s*4 + ht)*2 + 1)*64];
      f32x4* ac = (ht == 0) ? &acc0 : (ht == 1) ? &acc1 : (ht == 2) ? &acc2 : &acc3;
      *ac = __builtin_amdgcn_mfma_f32_16x16x32_bf16(ahi.v, whi.v, *ac, 0, 0, 0);
      *ac = __builtin_amdgcn_mfma_f32_16x16x32_bf16(alo.v, whi.v, *ac, 0, 0, 0);
      *ac = __builtin_amdgcn_mfma_f32_16x16x32_bf16(ahi.v, wlo.v, *ac, 0, 0, 0);
    }
  }

  // epilogue: per-tile wave-sync transpose through LDS, coalesced bf16 stores
  const int n = n0base + nl;
  const bool nvalid = (unsigned)n < (unsigned)Nc;
  const int S = slabh * Mc;                 // scalar row stride (h)
  unsigned short* hhp = hh + ((size_t)b*Hc)*S + (size_t)(lr0 + nl)*Mc
                  + (m0b + (w & 1)*16 + cl) + (size_t)g*S;

  const f32x4 accs[4] = {acc0, acc1, acc2, acc3};
  #pragma unroll
  for (int ht = 0; ht < 4; ++ht) {
    #pragma unroll
    for (int r = 0; r < 4; ++r) ldsT[w][cl][g*4 + r] = accs[ht][r];
    // same-wave LDS: compiler-inserted lgkmcnt wait orders write->read
    #pragma unroll
    for (int p = 0; p < 4; ++p) {
      const int hl2 = p*4 + g;
      const int h = ht*16 + hl2;
      if (h < Hc && nvalid) {
        const float v = fmaxf(ldsT[w][hl2][cl] + biasl[h], 0.f);
        hhp[(size_t)((ht*16 + p*4) * S)] = f2bf_rne(v);
      }
    }
  }
}

// ---------------------------------------------------------------------------
// k_conv v3: 7x7 conv partial sums over an h-GROUP (25 channels).
// blockIdx.z: b = z>>1, group g = z&1 -> 1024 blocks (4/CU, 16 waves/CU).
// Input hh is bf16; LDS tile f32 [38][40]; partials to part0/part1 (f32).
// Epilogue (sigmoid/weight/stats) moved to k_post.
// ---------------------------------------------------------------------------
__global__ __launch_bounds__(256) void k_conv(
    const unsigned short* __restrict__ hh, const float* __restrict__ cw,
    float* __restrict__ part0, float* __restrict__ part1,
    int n_begin, int slabh)
{
  __shared__ float tile[2][38*40];
  const int t  = threadIdx.x;
  const int b  = blockIdx.z >> 1;
  const int g  = blockIdx.z & 1;
  const int n0 = n_begin + blockIdx.y * 32;
  const int m0 = blockIdx.x * 32;

  const int rr = t >> 3;        // 0..31
  const int c0 = 4 * (t & 7);   // 0..28

  float stg[6];
  auto issue = [&](int h) {
    #pragma unroll
    for (int it = 0; it < 6; ++it) {
      const int idx = it*256 + t;
      float v = 0.f;
      if (idx < 38*38) {
        const int r = idx / 38, c = idx - r*38;
        const int gn = n0 - 3 + r, gm = m0 - 3 + c;
        if ((unsigned)gn < (unsigned)Nc && (unsigned)gm < (unsigned)Mc)
          v = __uint_as_float(
              (unsigned)hh[(((size_t)(b*Hc + h))*slabh + (gn - n_begin + 3))*Mc + gm] << 16);
      }
      stg[it] = v;
    }
  };
  auto commit = [&](int buf) {
    #pragma unroll
    for (int it = 0; it < 6; ++it) {
      const int idx = it*256 + t;
      if (idx < 38*38) {
        const int r = idx / 38, c = idx - r*38;
        tile[buf][r*40 + c] = stg[it];
      }
    }
  };

  const int h0 = g * 25;
  issue(h0); commit(0);
  __syncthreads();

  float acc0 = 0.f, acc1 = 0.f, acc2 = 0.f, acc3 = 0.f;
  for (int hi = 0; hi < 25; ++hi) {
    if (hi + 1 < 25) issue(h0 + hi + 1);
    const int buf = hi & 1;
    const float* __restrict__ cp = cw + (h0 + hi)*49;
    #pragma unroll
    for (int dn = 0; dn < 7; ++dn) {
      const float* tp = &tile[buf][(rr+dn)*40 + c0];
      const float4 wa = *(const float4*)tp;
      const float4 wb = *(const float4*)(tp+4);
      const float2 wc = *(const float2*)(tp+8);
      const float w_[10] = {wa.x,wa.y,wa.z,wa.w, wb.x,wb.y,wb.z,wb.w, wc.x,wc.y};
      #pragma unroll
      for (int dm = 0; dm < 7; ++dm) {
        const float wv = cp[dn*7 + dm];       // wave-uniform -> s_load
        acc0 = fmaf(w_[dm],   wv, acc0);
        acc1 = fmaf(w_[dm+1], wv, acc1);
        acc2 = fmaf(w_[dm+2], wv, acc2);
        acc3 = fmaf(w_[dm+3], wv, acc3);
      }
    }
    // commit writes the OTHER buffer: one barrier per h
    if (hi + 1 < 25) { commit((hi+1) & 1); __syncthreads(); }
  }

  float* __restrict__ dst = g ? part1 : part0;
  const int n = n0 + rr;
  float4 v; v.x = acc0; v.y = acc1; v.z = acc2; v.w = acc3;
  *(float4*)&dst[((size_t)b*Nc + n)*Mc + (m0 + c0)] = v;
}

// ---------------------------------------------------------------------------
// k_post: combine partials + conv bias -> sigmoid -> positional weight ->
// yhat store + sum/sumsq block reduction (f64 atomics).
// ---------------------------------------------------------------------------
__global__ __launch_bounds__(256) void k_post(
    const float* __restrict__ part0, const float* __restrict__ part1,
    const float* __restrict__ cb, const float* __restrict__ theta,
    const float* __restrict__ lam, float* __restrict__ yhat,
    double* __restrict__ gacc)
{
  __shared__ double red[2][4];
  const int t = threadIdx.x;
  const int px0 = (blockIdx.x*256 + t)*2;
  const int b = px0 >> 18;              // 262144 px per batch
  const int p = px0 & 262143;
  const int n = p >> 9, m = p & 511;

  const float2 pa = *(const float2*)&part0[px0];
  const float2 pb = *(const float2*)&part1[px0];
  const float cbv = cb[0], th = theta[0], lm = lam[0];
  const float half1 = 0.5f * (float)(Nc + 1);   // 256.5
  const float inv   = 1.0f / half1;
  const float ti = ((float)(n+1) - half1) * inv;
  const float av = expf(-lm * ti * ti);

  const float a_[2] = {pa.x + pb.x, pa.y + pb.y};
  float y[2]; double s = 0.0, ss = 0.0;
  #pragma unroll
  for (int j = 0; j < 2; ++j) {
    const float tj = ((float)(m+1+j) - half1) * inv;
    const float bv = expf(-lm * tj * tj);
    const float sg = 1.f / (1.f + expf(-(a_[j] + cbv)));
    y[j] = sg * ((1.f - th) * av * bv + th);
    s  += (double)y[j];
    ss += (double)y[j] * (double)y[j];
  }
  float2 yv; yv.x = y[0]; yv.y = y[1];
  *(float2*)&yhat[px0] = yv;

  for (int off = 32; off > 0; off >>= 1) {
    s  += __shfl_down(s,  off);
    ss += __shfl_down(ss, off);
  }
  const int wave = t >> 6, lane = t & 63;
  if (lane == 0) { red[0][wave] = s; red[1][wave] = ss; }
  __syncthreads();
  if (t == 0) {
    atomicAdd(&gacc[b*4 + 0], red[0][0] + red[0][1] + red[0][2] + red[0][3]);
    atomicAdd(&gacc[b*4 + 1], red[1][0] + red[1][1] + red[1][2] + red[1][3]);
  }
}

// ---------------------------------------------------------------------------
// k_q: Q = relu(yhat - mu - gamma*var); accumulate sum(Q)/count(Q>0);
// last block (atomic ticket) computes the final logistic outputs.
// ---------------------------------------------------------------------------
__global__ __launch_bounds__(256) void k_q(
    const float* __restrict__ yhat, double* __restrict__ gacc,
    const float* __restrict__ gamma, float* __restrict__ out,
    int* __restrict__ counter)
{
  const int tid = blockIdx.x * 256 + threadIdx.x;
  const int b = blockIdx.x >> 8;    // 256 blocks per batch
  const float4 y = ((const float4*)yhat)[tid];
  const double sum = gacc[b*4 + 0], ssq = gacc[b*4 + 1];
  const double mu  = sum / (double)NMc;
  const double var = (ssq - sum * mu) / ((double)NMc - 1.0);
  const double thr = mu + (double)gamma[0] * var;

  double sq = 0.0; int c = 0;
  double q;
  q = (double)y.x - thr; if (q > 0.0) { sq += q; ++c; }
  q = (double)y.y - thr; if (q > 0.0) { sq += q; ++c; }
  q = (double)y.z - thr; if (q > 0.0) { sq += q; ++c; }
  q = (double)y.w - thr; if (q > 0.0) { sq += q; ++c; }

  for (int off = 32; off > 0; off >>= 1) {
    sq += __shfl_down(sq, off);
    c  += __shfl_down(c,  off);
  }
  __shared__ double sr[4];
  __shared__ int    cr[4];
  const int wave = threadIdx.x >> 6, lane = threadIdx.x & 63;
  if (lane == 0) { sr[wave] = sq; cr[wave] = c; }
  __syncthreads();
  if (threadIdx.x == 0) {
    atomicAdd(&gacc[b*4 + 2], sr[0] + sr[1] + sr[2] + sr[3]);
    atomicAdd(&gacc[b*4 + 3], (double)(cr[0] + cr[1] + cr[2] + cr[3]));
    __threadfence();
    const int ticket = atomicAdd(counter, 1);
    if (ticket == 511) {              // last block: all atomics visible
      __threadfence();
      #pragma unroll
      for (int bb = 0; bb < Bc; ++bb) {
        const double phat = gacc[bb*4 + 2] / (gacc[bb*4 + 3] + 1.0);
        double v = 1.0 / (1.0 + exp(-20.0 * (phat - 0.5)));
        v = fmin(fmax(v, 0.0), 1.0);
        out[bb] = (float)v;
      }
    }
  }
}

// ---------------------------------------------------------------------------
extern "C" void kernel_launch(void* const* d_in, const int* in_sizes, int n_in,
                              void* d_out, int out_size, void* d_ws, size_t ws_size,
                              hipStream_t stream)
{
  const float* x0 = (const float*)d_in[0];
  const float* x1 = (const float*)d_in[1];
  const float* Wp = (const float*)d_in[2];
  const float* bp = (const float*)d_in[3];
  const float* Wh = (const float*)d_in[4];
  const float* bh = (const float*)d_in[5];
  const float* cw = (const float*)d_in[6];
  const float* cb = (const float*)d_in[7];
  const float* th = (const float*)d_in[8];
  const float* lm = (const float*)d_in[9];
  const float* gm = (const float*)d_in[10];
  float* out = (float*)d_out;
  (void)in_sizes; (void)n_in; (void)out_size;

  // adaptive slabbing: hh (bf16) = slabh*102400 B; pick largest that fits
  // total = 1 MiB + hh + 4 MiB parts + 2 MiB yhat
  int slabrows, nslab;
  if      (ws_size >= (size_t)62000000) { slabrows = 512; nslab = 1; }
  else if (ws_size >= (size_t)35000000) { slabrows = 256; nslab = 2; }
  else                                   { slabrows = 128; nslab = 4; }
  const int slabh = slabrows + 6;
  const size_t hh_bytes = (size_t)slabh * 102400;  // 2*50*slabh*512*2

  char* ws = (char*)d_ws;
  float*  e0   = (float*)(ws);                           // 409,600 B
  float*  e1   = (float*)(ws + 409600);                  // 409,600 B
  double* gacc = (double*)(ws + 819200);                 // 128 B (8 dbl + counter)
  int*    cnt  = (int*)(ws + 819200 + 64);
  uint4*  wsp  = (uint4*)(ws + 884736);                  // 57,344 B
  unsigned short* hh = (unsigned short*)(ws + 1048576);
  float*  part0 = (float*)(ws + 1048576 + hh_bytes);     // 2,097,152 B
  float*  part1 = part0 + (size_t)Bc*Nc*Mc;              // 2,097,152 B
  float*  yhat  = part1 + (size_t)Bc*Nc*Mc;              // 2,097,152 B

  k_prep<<<dim3(257), dim3(512), 0, stream>>>(x0, x1, Wp, bp, Wh, e0, e1, wsp, gacc);
  for (int s = 0; s < nslab; ++s) {
    const int n_begin = s * slabrows;
    k_hh  <<<dim3(16, slabh/2, 2), dim3(256), 0, stream>>>(
        e0, e1, wsp, bh, hh, n_begin - 3, slabh);
    k_conv<<<dim3(16, slabrows / 32, 4), dim3(256), 0, stream>>>(
        hh, cw, part0, part1, n_begin, slabh);
  }
  k_post<<<dim3(1024), dim3(256), 0, stream>>>(part0, part1, cb, th, lm, yhat, gacc);
  k_q   <<<dim3(512),  dim3(256), 0, stream>>>(yhat, gacc, gm, out, cnt);
}